// Round 11
// baseline (164.899 us; speedup 1.0000x reference)
//
#include <hip/hip_runtime.h>

#define N_NODES 50000
#define E_EDGES 1600000
#define ETOT    (E_EDGES + N_NODES)
#define DIN  128
#define DOUT 128
#define NH   4
#define HD   32

typedef unsigned short ushort_t;
typedef unsigned int uint_t;
typedef __attribute__((ext_vector_type(8))) short bfrag;   // 8 bf16 (4 VGPRs)
typedef __attribute__((ext_vector_type(4))) float ffrag;   // 4 fp32 acc

__device__ __forceinline__ ushort_t f2bf(float f) {
  uint_t u = __float_as_uint(f);
  u += 0x7fffu + ((u >> 16) & 1u);   // RNE
  return (ushort_t)(u >> 16);
}
__device__ __forceinline__ float bf_lo(uint_t u) {
  return __uint_as_float(u << 16);
}
__device__ __forceinline__ float bf_hi(uint_t u) {
  return __uint_as_float(u & 0xffff0000u);
}

// ---------------- K1: fused cast + GEMM(MFMA) + att-logits (r10 proven) ----
__global__ __launch_bounds__(256, 4) void gemm_att_kernel(
    const float* __restrict__ x, const float* __restrict__ W,
    const float* __restrict__ att_src, const float* __restrict__ att_dst,
    ushort_t* __restrict__ hb, float* __restrict__ a_src,
    float* __restrict__ a_dst) {
  __shared__ ushort_t Ws[DIN * DOUT];   // 32 KB bf16
  const int tid = threadIdx.x;
  for (int u = tid; u < 2048; u += 256) {
    int row = u >> 4;
    float4 w0 = *(const float4*)&W[u * 8];
    float4 w1 = *(const float4*)&W[u * 8 + 4];
    uint4 pk;
    pk.x = (uint_t)f2bf(w0.x) | ((uint_t)f2bf(w0.y) << 16);
    pk.y = (uint_t)f2bf(w0.z) | ((uint_t)f2bf(w0.w) << 16);
    pk.z = (uint_t)f2bf(w1.x) | ((uint_t)f2bf(w1.y) << 16);
    pk.w = (uint_t)f2bf(w1.z) | ((uint_t)f2bf(w1.w) << 16);
    *(uint4*)&Ws[(u ^ (row & 7)) * 8] = pk;
  }
  __syncthreads();

  const int wv = tid >> 6, l = tid & 63;
  const int lr = l & 15, lg = l >> 4;
  const int nbase = blockIdx.x * 64 + wv * 16;
  int na = nbase + lr;
  if (na >= N_NODES) na = N_NODES - 1;
  const float* xrow = x + (size_t)na * DIN;

  ffrag acc[8];
#pragma unroll
  for (int oc = 0; oc < 8; oc++) acc[oc] = (ffrag){0.f, 0.f, 0.f, 0.f};

#pragma unroll
  for (int kt = 0; kt < 4; kt++) {
    float4 x0 = *(const float4*)&xrow[kt * 32 + lg * 8];
    float4 x1 = *(const float4*)&xrow[kt * 32 + lg * 8 + 4];
    bfrag a;
    a[0] = (short)f2bf(x0.x); a[1] = (short)f2bf(x0.y);
    a[2] = (short)f2bf(x0.z); a[3] = (short)f2bf(x0.w);
    a[4] = (short)f2bf(x1.x); a[5] = (short)f2bf(x1.y);
    a[6] = (short)f2bf(x1.z); a[7] = (short)f2bf(x1.w);
#pragma unroll
    for (int oc = 0; oc < 8; oc++) {
      const int u = ((oc * 16 + lr) << 4) + kt * 4 + lg;
      const bfrag b = *(const bfrag*)&Ws[(u ^ (lr & 7)) * 8];
      acc[oc] = __builtin_amdgcn_mfma_f32_16x16x32_bf16(a, b, acc[oc], 0, 0, 0);
    }
  }

#pragma unroll
  for (int oc = 0; oc < 8; oc++) {
#pragma unroll
    for (int j = 0; j < 4; j++) {
      int n = nbase + lg * 4 + j;
      if (n < N_NODES)
        hb[((size_t)n << 7) + oc * 16 + lr] = f2bf(acc[oc][j]);
    }
  }

  float asv[8], adv[8];
#pragma unroll
  for (int oc = 0; oc < 8; oc++) {
    asv[oc] = att_src[oc * 16 + lr];
    adv[oc] = att_dst[oc * 16 + lr];
  }
#pragma unroll
  for (int j = 0; j < 4; j++) {
    float ps[4] = {0.f, 0.f, 0.f, 0.f};
    float pd[4] = {0.f, 0.f, 0.f, 0.f};
#pragma unroll
    for (int oc = 0; oc < 8; oc++) {
      ps[oc >> 1] = fmaf(acc[oc][j], asv[oc], ps[oc >> 1]);
      pd[oc >> 1] = fmaf(acc[oc][j], adv[oc], pd[oc >> 1]);
    }
#pragma unroll
    for (int off = 1; off < 16; off <<= 1) {
#pragma unroll
      for (int hd = 0; hd < 4; hd++) {
        ps[hd] += __shfl_xor(ps[hd], off);
        pd[hd] += __shfl_xor(pd[hd], off);
      }
    }
    int n = nbase + lg * 4 + j;
    if (n < N_NODES && lr < 4) {
      float vs = lr == 0 ? ps[0] : lr == 1 ? ps[1] : lr == 2 ? ps[2] : ps[3];
      float vd = lr == 0 ? pd[0] : lr == 1 ? pd[1] : lr == 2 ? pd[2] : pd[3];
      a_src[n * NH + lr] = vs;
      a_dst[n * NH + lr] = vd;
    }
  }
}

// ---------------- CSR build: fixed-capacity buckets ----------------
#define BSZ   256
#define NBUCK ((N_NODES + BSZ - 1) / BSZ)       // 196
#define CAP   9216                               // per-bucket capacity (max ~8.7k)
#define EPB_A 8192
#define NBLK_A ((ETOT + EPB_A - 1) / EPB_A)     // 202
#define NCHUNK 13                                // src chunk = si>>12 (0..12)

// K2: bin edges into fixed bucket regions (round-10 proven)
__global__ __launch_bounds__(256) void binA_kernel(
    const int* __restrict__ ei, int* __restrict__ gcur,
    uint_t* __restrict__ ebuf) {
  __shared__ int hist[NBUCK];
  __shared__ int base[NBUCK];
  const int tid = threadIdx.x;
  const int e0 = blockIdx.x * EPB_A;
  const int e1 = min(e0 + EPB_A, ETOT);
  for (int i = tid; i < NBUCK; i += 256) hist[i] = 0;
  __syncthreads();
  for (int e = e0 + tid; e < e1; e += 256) {
    int di = (e < E_EDGES) ? ei[E_EDGES + e] : (e - E_EDGES);
    atomicAdd(&hist[di >> 8], 1);
  }
  __syncthreads();
  for (int i = tid; i < NBUCK; i += 256) {
    int c = hist[i];
    base[i] = (c > 0) ? (i * CAP + atomicAdd(&gcur[i], c)) : 0;
    hist[i] = 0;
  }
  __syncthreads();
  for (int e = e0 + tid; e < e1; e += 256) {
    int si, di;
    if (e < E_EDGES) { si = ei[e]; di = ei[E_EDGES + e]; }
    else             { si = e - E_EDGES; di = si; }
    int b = di >> 8;
    int pos = base[b] + atomicAdd(&hist[b], 1);
    if (pos < (b + 1) * CAP)   // capacity guard
      ebuf[pos] = ((uint_t)(di & 255) << 24) | (uint_t)si;
  }
}

// K3: per-bucket CSR + FULL softmax. Pass1: count keys + accumulate s[node][h]
// via a_src gathers. Scan -> rs/re. Pass2: place col + quantized weights
// w4 = 4 x u8, w = 1 + q/255 (w = e/s + 1 in (1,2]).
__global__ __launch_bounds__(512) void binB_kernel(
    const uint_t* __restrict__ ebuf, const int* __restrict__ gcur,
    const float* __restrict__ a_src, const float* __restrict__ a_dst,
    int* __restrict__ rs, int* __restrict__ re,
    int* __restrict__ col, uint_t* __restrict__ w4) {
  __shared__ int cnt[BSZ * NCHUNK];     // 13.3 KB
  __shared__ int roff[BSZ * NCHUNK];    // 13.3 KB
  __shared__ float s_lds[BSZ][NH];      // 4 KB
  __shared__ float ad_lds[BSZ][NH];     // 4 KB
  __shared__ int wsum2[4];
  const int b = blockIdx.x;
  const int tid = threadIdx.x;
  const int n0 = b << 8;
  const int nn = min(BSZ, N_NODES - n0);
  const int s0 = b * CAP;
  const int s1 = s0 + min(gcur[b], CAP);

  for (int k = tid; k < BSZ * NCHUNK; k += 512) cnt[k] = 0;
  for (int k = tid; k < BSZ * NH; k += 512) {
    ((float*)s_lds)[k] = 0.f;
    int nidx = n0 + (k >> 2);
    ((float*)ad_lds)[k] = (nidx < N_NODES) ? a_dst[nidx * NH + (k & 3)] : 0.f;
  }
  __syncthreads();

  // pass 1: key counts + denominator accumulation
  for (int i = s0 + tid; i < s1; i += 512) {
    uint_t p = ebuf[i];
    int ld = (int)(p >> 24);
    int si = (int)(p & 0xFFFFFFu);
    atomicAdd(&cnt[ld * NCHUNK + (si >> 12)], 1);
    int sic = si < N_NODES ? si : 0;
    float4 as = *(const float4*)(a_src + (size_t)sic * NH);
    float v0 = as.x + ad_lds[ld][0]; v0 = v0 > 0.f ? v0 : 0.2f * v0;
    float v1 = as.y + ad_lds[ld][1]; v1 = v1 > 0.f ? v1 : 0.2f * v1;
    float v2 = as.z + ad_lds[ld][2]; v2 = v2 > 0.f ? v2 : 0.2f * v2;
    float v3 = as.w + ad_lds[ld][3]; v3 = v3 > 0.f ? v3 : 0.2f * v3;
    atomicAdd(&s_lds[ld][0], __expf(v0));
    atomicAdd(&s_lds[ld][1], __expf(v1));
    atomicAdd(&s_lds[ld][2], __expf(v2));
    atomicAdd(&s_lds[ld][3], __expf(v3));
  }
  __syncthreads();

  // scan over node totals (tid < 256 participate; node = tid)
  int tot = 0, xx = 0;
  int pref[NCHUNK];
  if (tid < 256) {
#pragma unroll
    for (int k = 0; k < NCHUNK; k++) { pref[k] = tot; tot += cnt[tid * NCHUNK + k]; }
    xx = tot;
#pragma unroll
    for (int off = 1; off < 64; off <<= 1) {
      int y = __shfl_up(xx, off, 64);
      if ((tid & 63) >= off) xx += y;
    }
    if ((tid & 63) == 63) wsum2[tid >> 6] = xx;
  }
  __syncthreads();
  if (tid < 4) {
    int w = wsum2[tid];
#pragma unroll
    for (int off = 1; off < 4; off <<= 1) {
      int y = __shfl_up(w, off, 64);
      if (tid >= off) w += y;
    }
    wsum2[tid] = w;
  }
  __syncthreads();
  if (tid < 256) {
    int wo = (tid >> 6) == 0 ? 0 : wsum2[(tid >> 6) - 1];
    int nodebase = xx + wo - tot;   // exclusive within bucket
#pragma unroll
    for (int k = 0; k < NCHUNK; k++) roff[tid * NCHUNK + k] = nodebase + pref[k];
    if (tid < nn) {
      rs[n0 + tid] = s0 + nodebase;
      re[n0 + tid] = s0 + nodebase + tot;
    }
  }
  __syncthreads();
  for (int k = tid; k < BSZ * NCHUNK; k += 512) cnt[k] = 0;
  for (int k = tid; k < BSZ * NH; k += 512)
    ((float*)s_lds)[k] = 1.f / ((float*)s_lds)[k];   // inf for empty slots, never read
  __syncthreads();

  // pass 2: place col + quantized per-head weights
  for (int i = s0 + tid; i < s1; i += 512) {
    uint_t p = ebuf[i];
    int ld = (int)(p >> 24);
    int si = (int)(p & 0xFFFFFFu);
    int key = ld * NCHUNK + (si >> 12);
    int pos = atomicAdd(&cnt[key], 1);
    int q = s0 + roff[key] + pos;
    int sic = si < N_NODES ? si : 0;
    float4 as = *(const float4*)(a_src + (size_t)sic * NH);
    float v0 = as.x + ad_lds[ld][0]; v0 = v0 > 0.f ? v0 : 0.2f * v0;
    float v1 = as.y + ad_lds[ld][1]; v1 = v1 > 0.f ? v1 : 0.2f * v1;
    float v2 = as.z + ad_lds[ld][2]; v2 = v2 > 0.f ? v2 : 0.2f * v2;
    float v3 = as.w + ad_lds[ld][3]; v3 = v3 > 0.f ? v3 : 0.2f * v3;
    uint_t q0 = (uint_t)(__expf(v0) * s_lds[ld][0] * 255.f + 0.5f);
    uint_t q1 = (uint_t)(__expf(v1) * s_lds[ld][1] * 255.f + 0.5f);
    uint_t q2 = (uint_t)(__expf(v2) * s_lds[ld][2] * 255.f + 0.5f);
    uint_t q3 = (uint_t)(__expf(v3) * s_lds[ld][3] * 255.f + 0.5f);
    uint_t qw = q0 | (q1 << 8) | (q2 << 16) | (q3 << 24);
    if (q >= 0 && q < NBUCK * CAP) { col[q] = si; w4[q] = qw; }
  }
}

// ---------------- K4: aggregation = pure weighted gather (bf16 h) ----------
#define NPB 16
#define CH  16

__global__ __launch_bounds__(256, 8) void agg_kernel(
    const int* __restrict__ col, const uint_t* __restrict__ w4,
    const int* __restrict__ rs, const int* __restrict__ re,
    const ushort_t* __restrict__ hb, float* __restrict__ out) {
  __shared__ float w_lds[NPB][CH][NH];   // 4 KB
  __shared__ int   si_lds[NPB][CH];      // 1 KB
  const int tid  = threadIdx.x;
  const int slot = tid >> 4;
  const int t    = tid & 15;
  const int node = blockIdx.x * NPB + slot;   // 3125*16 == N_NODES exactly
  const int start = rs[node];
  const int deg   = re[node] - start;

  const int head = t >> 2;
  const int c8 = t << 3;
  const ushort_t* hc = hb + c8;
  float a0 = 0.f, a1 = 0.f, a2 = 0.f, a3 = 0.f;
  float a4 = 0.f, a5 = 0.f, a6 = 0.f, a7 = 0.f;

  for (int base_e = 0; base_e < deg; base_e += CH) {
    int nch = deg - base_e;
    if (nch > CH) nch = CH;
    if (t < nch) {
      int qi = start + base_e + t;
      int si = col[qi];
      si = si < N_NODES ? si : 0;    // defensive clamp
      si_lds[slot][t] = si;
      uint_t qw = w4[qi];
      w_lds[slot][t][0] = 1.f + (float)(qw & 255u)         * (1.f / 255.f);
      w_lds[slot][t][1] = 1.f + (float)((qw >> 8) & 255u)  * (1.f / 255.f);
      w_lds[slot][t][2] = 1.f + (float)((qw >> 16) & 255u) * (1.f / 255.f);
      w_lds[slot][t][3] = 1.f + (float)(qw >> 24)          * (1.f / 255.f);
    }
    __builtin_amdgcn_fence(__ATOMIC_ACQ_REL, "wavefront");
#pragma unroll 2
    for (int j = 0; j < nch; j++) {
      int si = si_lds[slot][j];
      float w = w_lds[slot][j][head];
      const uint4 hv = *(const uint4*)(hc + ((size_t)si << 7));
      a0 = fmaf(bf_lo(hv.x), w, a0);
      a1 = fmaf(bf_hi(hv.x), w, a1);
      a2 = fmaf(bf_lo(hv.y), w, a2);
      a3 = fmaf(bf_hi(hv.y), w, a3);
      a4 = fmaf(bf_lo(hv.z), w, a4);
      a5 = fmaf(bf_hi(hv.z), w, a5);
      a6 = fmaf(bf_lo(hv.w), w, a6);
      a7 = fmaf(bf_hi(hv.w), w, a7);
    }
    __builtin_amdgcn_fence(__ATOMIC_ACQ_REL, "wavefront");
  }
  float* op = out + ((size_t)node << 7) + c8;
  *(float4*)(op)     = make_float4(a0, a1, a2, a3);
  *(float4*)(op + 4) = make_float4(a4, a5, a6, a7);
}

extern "C" void kernel_launch(void* const* d_in, const int* in_sizes, int n_in,
                              void* d_out, int out_size, void* d_ws, size_t ws_size,
                              hipStream_t stream) {
  const float* x       = (const float*)d_in[0];
  const int*   ei      = (const int*)d_in[1];
  const float* W       = (const float*)d_in[2];
  const float* att_src = (const float*)d_in[3];
  const float* att_dst = (const float*)d_in[4];
  float* out = (float*)d_out;

  // ws: hb | a_src | a_dst | gcur | rs | re | col | w4 | ebuf   (~36.5 MB)
  ushort_t* hb = (ushort_t*)d_ws;
  float* a_src = (float*)(hb + (size_t)N_NODES * DOUT);
  float* a_dst = a_src + (size_t)N_NODES * NH;
  int* gcur    = (int*)(a_dst + (size_t)N_NODES * NH);    // NBUCK
  int* rs      = gcur + NBUCK;                            // N_NODES
  int* re      = rs + N_NODES;                            // N_NODES
  int* col     = re + N_NODES;                            // NBUCK*CAP
  uint_t* w4   = (uint_t*)(col + NBUCK * CAP);            // NBUCK*CAP
  uint_t* ebuf = w4 + (size_t)NBUCK * CAP;                // NBUCK*CAP

  hipMemsetAsync(gcur, 0, (size_t)NBUCK * sizeof(int), stream);

  binA_kernel<<<NBLK_A, 256, 0, stream>>>(ei, gcur, ebuf);
  gemm_att_kernel<<<(N_NODES + 63) / 64, 256, 0, stream>>>(
      x, W, att_src, att_dst, hb, a_src, a_dst);
  binB_kernel<<<NBUCK, 512, 0, stream>>>(ebuf, gcur, a_src, a_dst, rs, re, col, w4);
  agg_kernel<<<N_NODES / NPB, 256, 0, stream>>>(col, w4, rs, re, hb, out);
}

// Round 12
// 123.782 us; speedup vs baseline: 1.3322x; 1.3322x over previous
//
#include <hip/hip_runtime.h>

#define N_NODES 50000
#define E_EDGES 1600000
#define ETOT    (E_EDGES + N_NODES)
#define DIN  128
#define DOUT 128
#define NH   4
#define HD   32

typedef unsigned short ushort_t;
typedef unsigned int uint_t;
typedef __attribute__((ext_vector_type(8))) short bfrag;   // 8 bf16 (4 VGPRs)
typedef __attribute__((ext_vector_type(4))) float ffrag;   // 4 fp32 acc

__device__ __forceinline__ ushort_t f2bf(float f) {
  uint_t u = __float_as_uint(f);
  u += 0x7fffu + ((u >> 16) & 1u);   // RNE
  return (ushort_t)(u >> 16);
}
__device__ __forceinline__ float bf_lo(uint_t u) {
  return __uint_as_float(u << 16);
}
__device__ __forceinline__ float bf_hi(uint_t u) {
  return __uint_as_float(u & 0xffff0000u);
}

// ---------------- CSR build params ----------------
#define BSZ   256
#define NBUCK ((N_NODES + BSZ - 1) / BSZ)       // 196
#define CAP   10240                              // per-bucket region capacity
#define EPB_A 8192
#define NBLK_A ((ETOT + EPB_A - 1) / EPB_A)     // 202
#define NCHUNK 13                                // src chunk = si>>12 (0..12)

// ---------------- K1: role-split fused kernel ----------------
// blocks [0, NBLK_A): binA edge binning (round-10 proven body)
// blocks [NBLK_A, NBLK_A+782): cast+GEMM(MFMA)+att-logits (round-10 proven)
__global__ __launch_bounds__(256, 4) void fused_binA_gemm_kernel(
    const int* __restrict__ ei, int* __restrict__ gcur,
    uint_t* __restrict__ ebuf,
    const float* __restrict__ x, const float* __restrict__ W,
    const float* __restrict__ att_src, const float* __restrict__ att_dst,
    ushort_t* __restrict__ hb, float* __restrict__ a_src,
    float* __restrict__ a_dst) {
  __shared__ int hist[NBUCK];
  __shared__ int base[NBUCK];
  __shared__ ushort_t Ws[DIN * DOUT];   // 32 KB bf16
  const int tid = threadIdx.x;

  if (blockIdx.x < NBLK_A) {
    // ---------- binA role ----------
    const int e0 = blockIdx.x * EPB_A;
    const int e1 = min(e0 + EPB_A, ETOT);
    for (int i = tid; i < NBUCK; i += 256) hist[i] = 0;
    __syncthreads();
    for (int e = e0 + tid; e < e1; e += 256) {
      int di = (e < E_EDGES) ? ei[E_EDGES + e] : (e - E_EDGES);
      atomicAdd(&hist[di >> 8], 1);
    }
    __syncthreads();
    for (int i = tid; i < NBUCK; i += 256) {
      int c = hist[i];
      base[i] = (c > 0) ? (i * CAP + atomicAdd(&gcur[i], c)) : 0;
      hist[i] = 0;
    }
    __syncthreads();
    for (int e = e0 + tid; e < e1; e += 256) {
      int si, di;
      if (e < E_EDGES) { si = ei[e]; di = ei[E_EDGES + e]; }
      else             { si = e - E_EDGES; di = si; }
      int b = di >> 8;
      int pos = base[b] + atomicAdd(&hist[b], 1);
      if (pos < (b + 1) * CAP)   // capacity guard
        ebuf[pos] = ((uint_t)(di & 255) << 24) | (uint_t)si;
    }
    return;
  }

  // ---------- gemm_att role ----------
  const int gb = blockIdx.x - NBLK_A;
  for (int u = tid; u < 2048; u += 256) {
    int row = u >> 4;
    float4 w0 = *(const float4*)&W[u * 8];
    float4 w1 = *(const float4*)&W[u * 8 + 4];
    uint4 pk;
    pk.x = (uint_t)f2bf(w0.x) | ((uint_t)f2bf(w0.y) << 16);
    pk.y = (uint_t)f2bf(w0.z) | ((uint_t)f2bf(w0.w) << 16);
    pk.z = (uint_t)f2bf(w1.x) | ((uint_t)f2bf(w1.y) << 16);
    pk.w = (uint_t)f2bf(w1.z) | ((uint_t)f2bf(w1.w) << 16);
    *(uint4*)&Ws[(u ^ (row & 7)) * 8] = pk;
  }
  __syncthreads();

  const int wv = tid >> 6, l = tid & 63;
  const int lr = l & 15, lg = l >> 4;
  const int nbase = gb * 64 + wv * 16;
  int na = nbase + lr;
  if (na >= N_NODES) na = N_NODES - 1;
  const float* xrow = x + (size_t)na * DIN;

  ffrag acc[8];
#pragma unroll
  for (int oc = 0; oc < 8; oc++) acc[oc] = (ffrag){0.f, 0.f, 0.f, 0.f};

#pragma unroll
  for (int kt = 0; kt < 4; kt++) {
    float4 x0 = *(const float4*)&xrow[kt * 32 + lg * 8];
    float4 x1 = *(const float4*)&xrow[kt * 32 + lg * 8 + 4];
    bfrag a;
    a[0] = (short)f2bf(x0.x); a[1] = (short)f2bf(x0.y);
    a[2] = (short)f2bf(x0.z); a[3] = (short)f2bf(x0.w);
    a[4] = (short)f2bf(x1.x); a[5] = (short)f2bf(x1.y);
    a[6] = (short)f2bf(x1.z); a[7] = (short)f2bf(x1.w);
#pragma unroll
    for (int oc = 0; oc < 8; oc++) {
      const int u = ((oc * 16 + lr) << 4) + kt * 4 + lg;
      const bfrag b = *(const bfrag*)&Ws[(u ^ (lr & 7)) * 8];
      acc[oc] = __builtin_amdgcn_mfma_f32_16x16x32_bf16(a, b, acc[oc], 0, 0, 0);
    }
  }

#pragma unroll
  for (int oc = 0; oc < 8; oc++) {
#pragma unroll
    for (int j = 0; j < 4; j++) {
      int n = nbase + lg * 4 + j;
      if (n < N_NODES)
        hb[((size_t)n << 7) + oc * 16 + lr] = f2bf(acc[oc][j]);
    }
  }

  float asv[8], adv[8];
#pragma unroll
  for (int oc = 0; oc < 8; oc++) {
    asv[oc] = att_src[oc * 16 + lr];
    adv[oc] = att_dst[oc * 16 + lr];
  }
#pragma unroll
  for (int j = 0; j < 4; j++) {
    float ps[4] = {0.f, 0.f, 0.f, 0.f};
    float pd[4] = {0.f, 0.f, 0.f, 0.f};
#pragma unroll
    for (int oc = 0; oc < 8; oc++) {
      ps[oc >> 1] = fmaf(acc[oc][j], asv[oc], ps[oc >> 1]);
      pd[oc >> 1] = fmaf(acc[oc][j], adv[oc], pd[oc >> 1]);
    }
#pragma unroll
    for (int off = 1; off < 16; off <<= 1) {
#pragma unroll
      for (int hd = 0; hd < 4; hd++) {
        ps[hd] += __shfl_xor(ps[hd], off);
        pd[hd] += __shfl_xor(pd[hd], off);
      }
    }
    int n = nbase + lg * 4 + j;
    if (n < N_NODES && lr < 4) {
      float vs = lr == 0 ? ps[0] : lr == 1 ? ps[1] : lr == 2 ? ps[2] : ps[3];
      float vd = lr == 0 ? pd[0] : lr == 1 ? pd[1] : lr == 2 ? pd[2] : pd[3];
      a_src[n * NH + lr] = vs;
      a_dst[n * NH + lr] = vd;
    }
  }
}

// ---------------- K2: per-bucket CSR build (round-10 proven, NCHUNK=13) ----
__global__ __launch_bounds__(256) void binB_kernel(
    const uint_t* __restrict__ ebuf, const int* __restrict__ gcur,
    int* __restrict__ rs, int* __restrict__ re, int* __restrict__ col) {
  __shared__ int cnt[BSZ * NCHUNK];    // 13.3 KB
  __shared__ int roff[BSZ * NCHUNK];   // 13.3 KB
  __shared__ int wsum2[4];
  const int b = blockIdx.x;
  const int tid = threadIdx.x;
  const int ln = tid & 63, wv = tid >> 6;
  const int n0 = b << 8;
  const int nn = min(BSZ, N_NODES - n0);
  const int s0 = b * CAP;
  const int s1 = s0 + min(gcur[b], CAP);
  for (int k = tid; k < BSZ * NCHUNK; k += 256) cnt[k] = 0;
  __syncthreads();
  for (int i = s0 + tid; i < s1; i += 256) {
    uint_t p = ebuf[i];
    int key = (int)(p >> 24) * NCHUNK + (int)((p & 0xFFFFFFu) >> 12);
    atomicAdd(&cnt[key], 1);
  }
  __syncthreads();
  int pref[NCHUNK];
  int tot = 0;
#pragma unroll
  for (int k = 0; k < NCHUNK; k++) { pref[k] = tot; tot += cnt[tid * NCHUNK + k]; }
  int xx = tot;
#pragma unroll
  for (int off = 1; off < 64; off <<= 1) {
    int y = __shfl_up(xx, off, 64);
    if (ln >= off) xx += y;
  }
  if (ln == 63) wsum2[wv] = xx;
  __syncthreads();
  if (tid < 4) {
    int w = wsum2[tid];
#pragma unroll
    for (int off = 1; off < 4; off <<= 1) {
      int y = __shfl_up(w, off, 64);
      if (tid >= off) w += y;
    }
    wsum2[tid] = w;
  }
  __syncthreads();
  int wo = (wv == 0) ? 0 : wsum2[wv - 1];
  const int nodebase = xx + wo - tot;   // exclusive within bucket
#pragma unroll
  for (int k = 0; k < NCHUNK; k++) roff[tid * NCHUNK + k] = nodebase + pref[k];
  if (tid < nn) {
    rs[n0 + tid] = s0 + nodebase;
    re[n0 + tid] = s0 + nodebase + tot;
  }
  __syncthreads();
  for (int k = tid; k < BSZ * NCHUNK; k += 256) cnt[k] = 0;
  __syncthreads();
  for (int i = s0 + tid; i < s1; i += 256) {
    uint_t p = ebuf[i];
    int si = (int)(p & 0xFFFFFFu);
    int key = (int)(p >> 24) * NCHUNK + (si >> 12);
    int pos = atomicAdd(&cnt[key], 1);
    int q = s0 + roff[key] + pos;
    if (q >= 0 && q < NBUCK * CAP) col[q] = si;
  }
}

// ---------------- K3: fused softmax + gather aggregation (r10 + unroll4) ---
#define NPB 16
#define CH  16

__global__ __launch_bounds__(256, 8) void agg_kernel(
    const int* __restrict__ col, const int* __restrict__ rs,
    const int* __restrict__ re, const ushort_t* __restrict__ hb,
    const float* __restrict__ a_src, const float* __restrict__ a_dst,
    float* __restrict__ out) {
  __shared__ float w_lds[NPB][CH][NH];   // 4 KB
  __shared__ int   si_lds[NPB][CH];      // 1 KB
  const int tid  = threadIdx.x;
  const int slot = tid >> 4;
  const int t    = tid & 15;
  const int node = blockIdx.x * NPB + slot;   // 3125*16 == N_NODES exactly
  const int start = rs[node];
  const int deg   = re[node] - start;
  const float4 ad = *(const float4*)(a_dst + (size_t)node * NH);

  // phase 1: plain exp-sum per head (16 threads strided)
  float s0 = 0.f, s1 = 0.f, s2 = 0.f, s3 = 0.f;
  for (int j = t; j < deg; j += 16) {
    int si = col[start + j];
    si = si < N_NODES ? si : 0;
    float4 as = *(const float4*)(a_src + (size_t)si * NH);
    float v0 = as.x + ad.x; v0 = v0 > 0.f ? v0 : 0.2f * v0;
    float v1 = as.y + ad.y; v1 = v1 > 0.f ? v1 : 0.2f * v1;
    float v2 = as.z + ad.z; v2 = v2 > 0.f ? v2 : 0.2f * v2;
    float v3 = as.w + ad.w; v3 = v3 > 0.f ? v3 : 0.2f * v3;
    s0 += __expf(v0);
    s1 += __expf(v1);
    s2 += __expf(v2);
    s3 += __expf(v3);
  }
#pragma unroll
  for (int off = 1; off < 16; off <<= 1) {
    s0 += __shfl_xor(s0, off);
    s1 += __shfl_xor(s1, off);
    s2 += __shfl_xor(s2, off);
    s3 += __shfl_xor(s3, off);
  }
  const float i0 = 1.f / s0, i1 = 1.f / s1, i2 = 1.f / s2, i3 = 1.f / s3;

  const int head = t >> 2;
  const int c8 = t << 3;
  const ushort_t* hc = hb + c8;
  float a0 = 0.f, a1 = 0.f, a2 = 0.f, a3 = 0.f;
  float a4 = 0.f, a5 = 0.f, a6 = 0.f, a7 = 0.f;

  for (int base_e = 0; base_e < deg; base_e += CH) {
    int nch = deg - base_e;
    if (nch > CH) nch = CH;
    if (t < nch) {
      int si = col[start + base_e + t];
      si = si < N_NODES ? si : 0;
      si_lds[slot][t] = si;
      float4 as = *(const float4*)(a_src + (size_t)si * NH);
      float v0 = as.x + ad.x; v0 = v0 > 0.f ? v0 : 0.2f * v0;
      float v1 = as.y + ad.y; v1 = v1 > 0.f ? v1 : 0.2f * v1;
      float v2 = as.z + ad.z; v2 = v2 > 0.f ? v2 : 0.2f * v2;
      float v3 = as.w + ad.w; v3 = v3 > 0.f ? v3 : 0.2f * v3;
      w_lds[slot][t][0] = __expf(v0) * i0 + 1.f;
      w_lds[slot][t][1] = __expf(v1) * i1 + 1.f;
      w_lds[slot][t][2] = __expf(v2) * i2 + 1.f;
      w_lds[slot][t][3] = __expf(v3) * i3 + 1.f;
    }
    __builtin_amdgcn_fence(__ATOMIC_ACQ_REL, "wavefront");
#pragma unroll 4
    for (int j = 0; j < nch; j++) {
      int si = si_lds[slot][j];
      float w = w_lds[slot][j][head];
      const uint4 hv = *(const uint4*)(hc + ((size_t)si << 7));
      a0 = fmaf(bf_lo(hv.x), w, a0);
      a1 = fmaf(bf_hi(hv.x), w, a1);
      a2 = fmaf(bf_lo(hv.y), w, a2);
      a3 = fmaf(bf_hi(hv.y), w, a3);
      a4 = fmaf(bf_lo(hv.z), w, a4);
      a5 = fmaf(bf_hi(hv.z), w, a5);
      a6 = fmaf(bf_lo(hv.w), w, a6);
      a7 = fmaf(bf_hi(hv.w), w, a7);
    }
    __builtin_amdgcn_fence(__ATOMIC_ACQ_REL, "wavefront");
  }
  float* op = out + ((size_t)node << 7) + c8;
  *(float4*)(op)     = make_float4(a0, a1, a2, a3);
  *(float4*)(op + 4) = make_float4(a4, a5, a6, a7);
}

extern "C" void kernel_launch(void* const* d_in, const int* in_sizes, int n_in,
                              void* d_out, int out_size, void* d_ws, size_t ws_size,
                              hipStream_t stream) {
  const float* x       = (const float*)d_in[0];
  const int*   ei      = (const int*)d_in[1];
  const float* W       = (const float*)d_in[2];
  const float* att_src = (const float*)d_in[3];
  const float* att_dst = (const float*)d_in[4];
  float* out = (float*)d_out;

  // ws: hb | a_src | a_dst | gcur | rs | re | col | ebuf   (~31 MB)
  ushort_t* hb = (ushort_t*)d_ws;
  float* a_src = (float*)(hb + (size_t)N_NODES * DOUT);
  float* a_dst = a_src + (size_t)N_NODES * NH;
  int* gcur    = (int*)(a_dst + (size_t)N_NODES * NH);    // NBUCK
  int* rs      = gcur + NBUCK;                            // N_NODES
  int* re      = rs + N_NODES;                            // N_NODES
  int* col     = re + N_NODES;                            // NBUCK*CAP
  uint_t* ebuf = (uint_t*)(col + NBUCK * CAP);            // NBUCK*CAP

  hipMemsetAsync(gcur, 0, (size_t)NBUCK * sizeof(int), stream);

  const int gemm_blocks = (N_NODES + 63) / 64;   // 782
  fused_binA_gemm_kernel<<<NBLK_A + gemm_blocks, 256, 0, stream>>>(
      ei, gcur, ebuf, x, W, att_src, att_dst, hb, a_src, a_dst);
  binB_kernel<<<NBUCK, 256, 0, stream>>>(ebuf, gcur, rs, re, col);
  agg_kernel<<<N_NODES / NPB, 256, 0, stream>>>(col, rs, re, hb, a_src, a_dst, out);
}

// Round 13
// 105.258 us; speedup vs baseline: 1.5666x; 1.1760x over previous
//
#include <hip/hip_runtime.h>

#define N_NODES 50000
#define E_EDGES 1600000
#define ETOT    (E_EDGES + N_NODES)
#define DIN  128
#define DOUT 128
#define NH   4
#define HD   32

typedef unsigned short ushort_t;
typedef unsigned int uint_t;
typedef __attribute__((ext_vector_type(8))) short bfrag;   // 8 bf16 (4 VGPRs)
typedef __attribute__((ext_vector_type(4))) float ffrag;   // 4 fp32 acc

__device__ __forceinline__ ushort_t f2bf(float f) {
  uint_t u = __float_as_uint(f);
  u += 0x7fffu + ((u >> 16) & 1u);   // RNE
  return (ushort_t)(u >> 16);
}
__device__ __forceinline__ float bf_lo(uint_t u) {
  return __uint_as_float(u << 16);
}
__device__ __forceinline__ float bf_hi(uint_t u) {
  return __uint_as_float(u & 0xffff0000u);
}

// ---------------- CSR build params ----------------
#define BSZ   64
#define NBUCK ((N_NODES + BSZ - 1) / BSZ)       // 782
#define CAP   2560                               // per-bucket capacity (mean 2112)
#define EPB_A 4096
#define NBLK_A ((ETOT + EPB_A - 1) / EPB_A)     // 403
#define NCHUNK 13                                // src chunk = si>>12 (0..12)

// ---------------- K1: role-split fused kernel ----------------
// blocks [0, NBLK_A): binA edge binning; rest: cast+GEMM(MFMA)+att-logits.
__global__ __launch_bounds__(256, 4) void fused_binA_gemm_kernel(
    const int* __restrict__ ei, int* __restrict__ gcur,
    uint_t* __restrict__ ebuf,
    const float* __restrict__ x, const float* __restrict__ W,
    const float* __restrict__ att_src, const float* __restrict__ att_dst,
    ushort_t* __restrict__ hb, float* __restrict__ a_src,
    float* __restrict__ a_dst) {
  __shared__ int hist[NBUCK];
  __shared__ int base[NBUCK];
  __shared__ ushort_t Ws[DIN * DOUT];   // 32 KB bf16
  const int tid = threadIdx.x;

  if (blockIdx.x < NBLK_A) {
    // ---------- binA role ----------
    const int e0 = blockIdx.x * EPB_A;
    const int e1 = min(e0 + EPB_A, ETOT);
    for (int i = tid; i < NBUCK; i += 256) hist[i] = 0;
    __syncthreads();
    for (int e = e0 + tid; e < e1; e += 256) {
      int di = (e < E_EDGES) ? ei[E_EDGES + e] : (e - E_EDGES);
      atomicAdd(&hist[di >> 6], 1);
    }
    __syncthreads();
    for (int i = tid; i < NBUCK; i += 256) {
      int c = hist[i];
      base[i] = (c > 0) ? (i * CAP + atomicAdd(&gcur[i], c)) : 0;
      hist[i] = 0;
    }
    __syncthreads();
    for (int e = e0 + tid; e < e1; e += 256) {
      int si, di;
      if (e < E_EDGES) { si = ei[e]; di = ei[E_EDGES + e]; }
      else             { si = e - E_EDGES; di = si; }
      int b = di >> 6;
      int pos = base[b] + atomicAdd(&hist[b], 1);
      if (pos < (b + 1) * CAP)   // capacity guard: drop -> absmax catches
        ebuf[pos] = ((uint_t)(di & 63) << 24) | (uint_t)si;
    }
    return;
  }

  // ---------- gemm_att role ----------
  const int gb = blockIdx.x - NBLK_A;
  for (int u = tid; u < 2048; u += 256) {
    int row = u >> 4;
    float4 w0 = *(const float4*)&W[u * 8];
    float4 w1 = *(const float4*)&W[u * 8 + 4];
    uint4 pk;
    pk.x = (uint_t)f2bf(w0.x) | ((uint_t)f2bf(w0.y) << 16);
    pk.y = (uint_t)f2bf(w0.z) | ((uint_t)f2bf(w0.w) << 16);
    pk.z = (uint_t)f2bf(w1.x) | ((uint_t)f2bf(w1.y) << 16);
    pk.w = (uint_t)f2bf(w1.z) | ((uint_t)f2bf(w1.w) << 16);
    *(uint4*)&Ws[(u ^ (row & 7)) * 8] = pk;
  }
  __syncthreads();

  const int wv = tid >> 6, l = tid & 63;
  const int lr = l & 15, lg = l >> 4;
  const int nbase = gb * 64 + wv * 16;
  int na = nbase + lr;
  if (na >= N_NODES) na = N_NODES - 1;
  const float* xrow = x + (size_t)na * DIN;

  ffrag acc[8];
#pragma unroll
  for (int oc = 0; oc < 8; oc++) acc[oc] = (ffrag){0.f, 0.f, 0.f, 0.f};

#pragma unroll
  for (int kt = 0; kt < 4; kt++) {
    float4 x0 = *(const float4*)&xrow[kt * 32 + lg * 8];
    float4 x1 = *(const float4*)&xrow[kt * 32 + lg * 8 + 4];
    bfrag a;
    a[0] = (short)f2bf(x0.x); a[1] = (short)f2bf(x0.y);
    a[2] = (short)f2bf(x0.z); a[3] = (short)f2bf(x0.w);
    a[4] = (short)f2bf(x1.x); a[5] = (short)f2bf(x1.y);
    a[6] = (short)f2bf(x1.z); a[7] = (short)f2bf(x1.w);
#pragma unroll
    for (int oc = 0; oc < 8; oc++) {
      const int u = ((oc * 16 + lr) << 4) + kt * 4 + lg;
      const bfrag b = *(const bfrag*)&Ws[(u ^ (lr & 7)) * 8];
      acc[oc] = __builtin_amdgcn_mfma_f32_16x16x32_bf16(a, b, acc[oc], 0, 0, 0);
    }
  }

#pragma unroll
  for (int oc = 0; oc < 8; oc++) {
#pragma unroll
    for (int j = 0; j < 4; j++) {
      int n = nbase + lg * 4 + j;
      if (n < N_NODES)
        hb[((size_t)n << 7) + oc * 16 + lr] = f2bf(acc[oc][j]);
    }
  }

  float asv[8], adv[8];
#pragma unroll
  for (int oc = 0; oc < 8; oc++) {
    asv[oc] = att_src[oc * 16 + lr];
    adv[oc] = att_dst[oc * 16 + lr];
  }
#pragma unroll
  for (int j = 0; j < 4; j++) {
    float ps[4] = {0.f, 0.f, 0.f, 0.f};
    float pd[4] = {0.f, 0.f, 0.f, 0.f};
#pragma unroll
    for (int oc = 0; oc < 8; oc++) {
      ps[oc >> 1] = fmaf(acc[oc][j], asv[oc], ps[oc >> 1]);
      pd[oc >> 1] = fmaf(acc[oc][j], adv[oc], pd[oc >> 1]);
    }
#pragma unroll
    for (int off = 1; off < 16; off <<= 1) {
#pragma unroll
      for (int hd = 0; hd < 4; hd++) {
        ps[hd] += __shfl_xor(ps[hd], off);
        pd[hd] += __shfl_xor(pd[hd], off);
      }
    }
    int n = nbase + lg * 4 + j;
    if (n < N_NODES && lr < 4) {
      float vs = lr == 0 ? ps[0] : lr == 1 ? ps[1] : lr == 2 ? ps[2] : ps[3];
      float vd = lr == 0 ? pd[0] : lr == 1 ? pd[1] : lr == 2 ? pd[2] : pd[3];
      a_src[n * NH + lr] = vs;
      a_dst[n * NH + lr] = vd;
    }
  }
}

// ---------------- K2: per-bucket CSR build (BSZ=64, single-wave scan) ------
__global__ __launch_bounds__(256) void binB_kernel(
    const uint_t* __restrict__ ebuf, const int* __restrict__ gcur,
    int* __restrict__ rs, int* __restrict__ re, int* __restrict__ col) {
  __shared__ int cnt[BSZ * NCHUNK];    // 832 ints
  __shared__ int roff[BSZ * NCHUNK];
  const int b = blockIdx.x;
  const int tid = threadIdx.x;
  const int n0 = b << 6;
  const int nn = min(BSZ, N_NODES - n0);
  const int s0 = b * CAP;
  const int s1 = s0 + min(gcur[b], CAP);
  for (int k = tid; k < BSZ * NCHUNK; k += 256) cnt[k] = 0;
  __syncthreads();
  for (int i = s0 + tid; i < s1; i += 256) {
    uint_t p = ebuf[i];
    int key = (int)(p >> 24) * NCHUNK + (int)((p & 0xFFFFFFu) >> 12);
    atomicAdd(&cnt[key], 1);
  }
  __syncthreads();
  if (tid < BSZ) {   // one wave: node = tid
    int pref[NCHUNK];
    int tot = 0;
#pragma unroll
    for (int k = 0; k < NCHUNK; k++) { pref[k] = tot; tot += cnt[tid * NCHUNK + k]; }
    int xx = tot;
#pragma unroll
    for (int off = 1; off < 64; off <<= 1) {
      int y = __shfl_up(xx, off, 64);
      if (tid >= off) xx += y;
    }
    const int nodebase = xx - tot;   // exclusive
#pragma unroll
    for (int k = 0; k < NCHUNK; k++) roff[tid * NCHUNK + k] = nodebase + pref[k];
    if (tid < nn) {
      rs[n0 + tid] = s0 + nodebase;
      re[n0 + tid] = s0 + nodebase + tot;
    }
  }
  __syncthreads();
  for (int k = tid; k < BSZ * NCHUNK; k += 256) cnt[k] = 0;
  __syncthreads();
  for (int i = s0 + tid; i < s1; i += 256) {
    uint_t p = ebuf[i];
    int si = (int)(p & 0xFFFFFFu);
    int key = (int)(p >> 24) * NCHUNK + (si >> 12);
    int pos = atomicAdd(&cnt[key], 1);
    int q = s0 + roff[key] + pos;
    if (q >= 0 && q < NBUCK * CAP) col[q] = si;
  }
}

// ---------------- K3: SINGLE-PASS aggregation ----------------
// out = (sum e_i*h_i)/s + sum h_i,  e_i = exp(leaky(alpha_i)), s = sum e_i.
// One sweep: staging computes e once/edge; gather accumulates acc1, acc2, s.
#define NPB 16
#define CH  16

__global__ __launch_bounds__(256, 8) void agg_kernel(
    const int* __restrict__ col, const int* __restrict__ rs,
    const int* __restrict__ re, const ushort_t* __restrict__ hb,
    const float* __restrict__ a_src, const float* __restrict__ a_dst,
    float* __restrict__ out) {
  __shared__ float w_lds[NPB][CH][NH];   // 4 KB (unnormalized e)
  __shared__ int   si_lds[NPB][CH];      // 1 KB
  const int tid  = threadIdx.x;
  const int slot = tid >> 4;
  const int t    = tid & 15;
  const int node = blockIdx.x * NPB + slot;   // 3125*16 == N_NODES exactly
  const int start = rs[node];
  const int deg   = re[node] - start;
  const float4 ad = *(const float4*)(a_dst + (size_t)node * NH);

  const int head = t >> 2;
  const int c8 = t << 3;
  const ushort_t* hc = hb + c8;
  float s = 0.f;
  float a0 = 0.f, a1 = 0.f, a2 = 0.f, a3 = 0.f;
  float a4 = 0.f, a5 = 0.f, a6 = 0.f, a7 = 0.f;
  float b0 = 0.f, b1 = 0.f, b2 = 0.f, b3 = 0.f;
  float b4 = 0.f, b5 = 0.f, b6 = 0.f, b7 = 0.f;

  for (int base_e = 0; base_e < deg; base_e += CH) {
    int nch = deg - base_e;
    if (nch > CH) nch = CH;
    if (t < nch) {
      int si = col[start + base_e + t];
      si = si < N_NODES ? si : 0;    // defensive clamp
      si_lds[slot][t] = si;
      float4 as = *(const float4*)(a_src + (size_t)si * NH);
      float v0 = as.x + ad.x; v0 = v0 > 0.f ? v0 : 0.2f * v0;
      float v1 = as.y + ad.y; v1 = v1 > 0.f ? v1 : 0.2f * v1;
      float v2 = as.z + ad.z; v2 = v2 > 0.f ? v2 : 0.2f * v2;
      float v3 = as.w + ad.w; v3 = v3 > 0.f ? v3 : 0.2f * v3;
      w_lds[slot][t][0] = __expf(v0);
      w_lds[slot][t][1] = __expf(v1);
      w_lds[slot][t][2] = __expf(v2);
      w_lds[slot][t][3] = __expf(v3);
    }
    __builtin_amdgcn_fence(__ATOMIC_ACQ_REL, "wavefront");
#pragma unroll 2
    for (int j = 0; j < nch; j++) {
      int si = si_lds[slot][j];
      float e = w_lds[slot][j][head];
      s += e;
      const uint4 hv = *(const uint4*)(hc + ((size_t)si << 7));
      float h0 = bf_lo(hv.x), h1 = bf_hi(hv.x);
      float h2 = bf_lo(hv.y), h3 = bf_hi(hv.y);
      float h4 = bf_lo(hv.z), h5 = bf_hi(hv.z);
      float h6 = bf_lo(hv.w), h7 = bf_hi(hv.w);
      a0 = fmaf(h0, e, a0); b0 += h0;
      a1 = fmaf(h1, e, a1); b1 += h1;
      a2 = fmaf(h2, e, a2); b2 += h2;
      a3 = fmaf(h3, e, a3); b3 += h3;
      a4 = fmaf(h4, e, a4); b4 += h4;
      a5 = fmaf(h5, e, a5); b5 += h5;
      a6 = fmaf(h6, e, a6); b6 += h6;
      a7 = fmaf(h7, e, a7); b7 += h7;
    }
    __builtin_amdgcn_fence(__ATOMIC_ACQ_REL, "wavefront");
  }
  const float inv = 1.0f / s;
  float* op = out + ((size_t)node << 7) + c8;
  *(float4*)(op)     = make_float4(fmaf(a0, inv, b0), fmaf(a1, inv, b1),
                                   fmaf(a2, inv, b2), fmaf(a3, inv, b3));
  *(float4*)(op + 4) = make_float4(fmaf(a4, inv, b4), fmaf(a5, inv, b5),
                                   fmaf(a6, inv, b6), fmaf(a7, inv, b7));
}

extern "C" void kernel_launch(void* const* d_in, const int* in_sizes, int n_in,
                              void* d_out, int out_size, void* d_ws, size_t ws_size,
                              hipStream_t stream) {
  const float* x       = (const float*)d_in[0];
  const int*   ei      = (const int*)d_in[1];
  const float* W       = (const float*)d_in[2];
  const float* att_src = (const float*)d_in[3];
  const float* att_dst = (const float*)d_in[4];
  float* out = (float*)d_out;

  // ws: hb | a_src | a_dst | gcur | rs | re | col | ebuf   (~30 MB)
  ushort_t* hb = (ushort_t*)d_ws;
  float* a_src = (float*)(hb + (size_t)N_NODES * DOUT);
  float* a_dst = a_src + (size_t)N_NODES * NH;
  int* gcur    = (int*)(a_dst + (size_t)N_NODES * NH);    // NBUCK
  int* rs      = gcur + NBUCK;                            // N_NODES
  int* re      = rs + N_NODES;                            // N_NODES
  int* col     = re + N_NODES;                            // NBUCK*CAP
  uint_t* ebuf = (uint_t*)(col + (size_t)NBUCK * CAP);    // NBUCK*CAP

  hipMemsetAsync(gcur, 0, (size_t)NBUCK * sizeof(int), stream);

  const int gemm_blocks = (N_NODES + 63) / 64;   // 782
  fused_binA_gemm_kernel<<<NBLK_A + gemm_blocks, 256, 0, stream>>>(
      ei, gcur, ebuf, x, W, att_src, att_dst, hb, a_src, a_dst);
  binB_kernel<<<NBUCK, 256, 0, stream>>>(ebuf, gcur, rs, re, col);
  agg_kernel<<<N_NODES / NPB, 256, 0, stream>>>(col, rs, re, hb, a_src, a_dst, out);
}